// Round 4
// baseline (59.779 us; speedup 1.0000x reference)
//
#include <hip/hip_runtime.h>
#include <math.h>

#define NBATCH 2048
#define GS 14
#define NCELL (GS * GS)      // 196
#define NCH 30
#define NPRED (NCELL * NCH)  // 5880 floats per batch
#define NQUAD (NPRED / 4)    // 1470 float4
#define MAXOBJ 20
#define NCLS 20

// ---------------------------------------------------------------------------
// Single fused kernel: one block per batch element.
//  - coalesced float4 staging of the 23.5 KB pred slab into linear LDS
//    (stride-30 rows -> scalar reads are ~2-way bank aliased = free)
//  - phase A (lanes 0..19): decode objects from global target -> LDS list
//    (independent of staging, shares its barrier)
//  - phase B (tid<196): per-cell scan of the object list in order ->
//    reproduces reference's sequential last-write-wins; noobj cells touch
//    only conf0/conf5; counts come from ballot+popc
//  - tail: 5-value shuffle reduce -> partials row; last-arriving block
//    (counter mod 2048, poison-proof) reduces 2048 rows, writes the loss
// partials[b*8+k]: 0=s_noobj 1=c_noobj 2=s_objconf 3=s_xy 4=s_wh 5=s_clc 6=c_obj
// ---------------------------------------------------------------------------
__global__ __launch_bounds__(256) void yolo_fused_kernel(
        const float* __restrict__ pred,
        const float* __restrict__ target,
        float* __restrict__ partials,
        unsigned int* __restrict__ counter,
        float* __restrict__ out)
{
    __shared__ float s_pred[NPRED];          // 23520 B, linear
    __shared__ int   s_obj_cell[MAXOBJ];
    __shared__ float s_obj_dat[MAXOBJ][4];   // offx,offy,w,h
    __shared__ int   s_obj_cls[MAXOBJ];
    __shared__ float s_red[4][8];
    __shared__ unsigned int s_last;

    const int b = blockIdx.x;
    const int tid = threadIdx.x;
    const float fg = (float)GS;

    // ---- stage pred slab: coalesced float4 -> linear LDS ----
    {
        const float4* g4 = (const float4*)(pred + (size_t)b * NPRED);
        float4* s4 = (float4*)s_pred;
        #pragma unroll
        for (int k = 0; k < 6; ++k) {
            int i = tid + k * 256;
            if (i < NQUAD) s4[i] = g4[i];
        }
    }

    // ---- phase A: object decode straight from global target ----
    if (tid < MAXOBJ) {
        const float* tb = target + (size_t)b * (MAXOBJ * 5) + tid * 5;
        float x1 = tb[0], y1 = tb[1], x2 = tb[2], y2 = tb[3], cf = tb[4];
        int cell = -1;
        float offx = 0.f, offy = 0.f, w = 0.f, h = 0.f;
        if ((x1 + y1 + x2 + y2 + cf) != 0.0f) {
            float cx = (x1 + x2) * 0.5f * fg;
            float cy = (y1 + y2) * 0.5f * fg;
            w = x2 - x1;
            h = y2 - y1;
            int gx = min(max((int)floorf(cx), 0), GS - 1);
            int gy = min(max((int)floorf(cy), 0), GS - 1);
            offx = cx - (float)gx;
            offy = cy - (float)gy;
            cell = gy * GS + gx;
        }
        s_obj_cell[tid] = cell;
        s_obj_dat[tid][0] = offx;
        s_obj_dat[tid][1] = offy;
        s_obj_dat[tid][2] = w;
        s_obj_dat[tid][3] = h;
        s_obj_cls[tid] = (int)cf;
    }
    __syncthreads();   // staging + phase A both complete

    // ---- phase B: per-cell resolution + loss partials ----
    float v0 = 0.f, v2 = 0.f, v3 = 0.f, v4 = 0.f, v5 = 0.f;
    int nset = -1;
    if (tid < NCELL) {
        const float* pc = &s_pred[tid * NCH];
        int flag0 = 0, flag1 = 0;
        float b0x = 0.f, b0y = 0.f, b0w = 0.f, b0h = 0.f;
        float b1x = 0.f, b1y = 0.f, b1w = 0.f, b1h = 0.f;
        unsigned int clsmask = 0u;
        #pragma unroll 1
        for (int o = 0; o < MAXOBJ; ++o) {
            if (s_obj_cell[o] == tid) {   // broadcast read; <=1 lane matches
                float offx = s_obj_dat[o][0], offy = s_obj_dat[o][1];
                float w = s_obj_dat[o][2],  h = s_obj_dat[o][3];
                float tcx = offx / fg, tcy = offy / fg;
                float tlx = tcx - 0.5f * w, tly = tcy - 0.5f * h;
                float trx = tcx + 0.5f * w, trY = tcy + 0.5f * h;
                float ta = (trx - tlx) * (trY - tly);
                float iou0, iou1;
                {
                    float px = pc[1] / fg, py = pc[2] / fg;
                    float pw = pc[3], ph = pc[4];
                    float plx = px - 0.5f * pw, ply = py - 0.5f * ph;
                    float prx = px + 0.5f * pw, prY = py + 0.5f * ph;
                    float ix = fmaxf(fminf(prx, trx) - fmaxf(plx, tlx), 0.f);
                    float iy = fmaxf(fminf(prY, trY) - fmaxf(ply, tly), 0.f);
                    float inter = ix * iy;
                    float a1 = (prx - plx) * (prY - ply);
                    iou0 = inter / (a1 + ta - inter);
                }
                {
                    float px = pc[6] / fg, py = pc[7] / fg;
                    float pw = pc[8], ph = pc[9];
                    float plx = px - 0.5f * pw, ply = py - 0.5f * ph;
                    float prx = px + 0.5f * pw, prY = py + 0.5f * ph;
                    float ix = fmaxf(fminf(prx, trx) - fmaxf(plx, tlx), 0.f);
                    float iy = fmaxf(fminf(prY, trY) - fmaxf(ply, tly), 0.f);
                    float inter = ix * iy;
                    float a1 = (prx - plx) * (prY - ply);
                    iou1 = inter / (a1 + ta - inter);
                }
                if (iou1 > iou0) { flag1 = 1; b1x = offx; b1y = offy; b1w = w; b1h = h; }
                else             { flag0 = 1; b0x = offx; b0y = offy; b0w = w; b0h = h; }
                clsmask |= 1u << s_obj_cls[o];
            }
        }
        nset = flag0 + flag1;
        if (nset == 0) {
            float c0 = pc[0], c1 = pc[5];
            v0 = c0 * c0 + c1 * c1;                       // only 2 LDS reads
        } else if (nset == 1) {
            float conf = flag1 ? pc[5] : pc[0];
            float px   = flag1 ? pc[6] : pc[1];
            float py   = flag1 ? pc[7] : pc[2];
            float pw   = flag1 ? pc[8] : pc[3];
            float ph   = flag1 ? pc[9] : pc[4];
            float bx = flag1 ? b1x : b0x;
            float by = flag1 ? b1y : b0y;
            float bw = flag1 ? b1w : b0w;
            float bh = flag1 ? b1h : b0h;
            float dconf = conf - 1.0f;
            v2 = dconf * dconf;
            float dx = px - bx, dy = py - by;
            v3 = dx * dx + dy * dy;
            float sw = sqrtf(pw) - sqrtf(bw);
            float sh = sqrtf(ph) - sqrtf(bh);
            v4 = sw * sw + sh * sh;
            float clc = 0.f;
            #pragma unroll
            for (int c = 0; c < NCLS; ++c) {
                float t = ((clsmask >> c) & 1u) ? 1.0f : 0.0f;
                float d = pc[10 + c] - t;
                clc += d * d;
            }
            v5 = clc;
        }
        // nset == 2: excluded from every loss term
    }

    // counts via ballot (uniform across the wave)
    unsigned long long bn = __ballot(nset == 0);
    unsigned long long bo = __ballot(nset == 1);

    // ---- 5-value wave shuffle reduce, cross-wave via LDS ----
    #pragma unroll
    for (int off = 32; off > 0; off >>= 1) {
        v0 += __shfl_down(v0, off);
        v2 += __shfl_down(v2, off);
        v3 += __shfl_down(v3, off);
        v4 += __shfl_down(v4, off);
        v5 += __shfl_down(v5, off);
    }
    const int wave = tid >> 6;
    if ((tid & 63) == 0) {
        s_red[wave][0] = v0;
        s_red[wave][1] = (float)__popcll(bn);
        s_red[wave][2] = v2;
        s_red[wave][3] = v3;
        s_red[wave][4] = v4;
        s_red[wave][5] = v5;
        s_red[wave][6] = (float)__popcll(bo);
    }
    __syncthreads();
    if (tid == 0) {
        float* p = partials + (size_t)b * 8;
        #pragma unroll
        for (int k = 0; k < 7; ++k)
            p[k] = s_red[0][k] + s_red[1][k] + s_red[2][k] + s_red[3][k];
        p[7] = 0.0f;
        __threadfence();                       // release partials
        unsigned int old = atomicAdd(counter, 1u);
        // mod-2048: exactly one last block per call for ANY initial counter
        // value (incl. 0xAA poison) since each call adds exactly 2048
        s_last = ((old & (NBATCH - 1)) == (NBATCH - 1)) ? 1u : 0u;
    }
    __syncthreads();

    // ---- last-arriving block: final reduction + loss formula ----
    if (s_last) {
        __threadfence();                       // acquire partials
        float f0 = 0.f, f1 = 0.f, f2 = 0.f, f3 = 0.f, f4 = 0.f, f5 = 0.f, f6 = 0.f;
        for (int r = tid; r < NBATCH; r += 256) {
            const float4* p = (const float4*)(partials + (size_t)r * 8);
            float4 x0 = p[0];
            float4 x1 = p[1];
            f0 += x0.x; f1 += x0.y; f2 += x0.z; f3 += x0.w;
            f4 += x1.x; f5 += x1.y; f6 += x1.z;
        }
        #pragma unroll
        for (int off = 32; off > 0; off >>= 1) {
            f0 += __shfl_down(f0, off);
            f1 += __shfl_down(f1, off);
            f2 += __shfl_down(f2, off);
            f3 += __shfl_down(f3, off);
            f4 += __shfl_down(f4, off);
            f5 += __shfl_down(f5, off);
            f6 += __shfl_down(f6, off);
        }
        if ((tid & 63) == 0) {
            s_red[wave][0] = f0; s_red[wave][1] = f1; s_red[wave][2] = f2;
            s_red[wave][3] = f3; s_red[wave][4] = f4; s_red[wave][5] = f5;
            s_red[wave][6] = f6;
        }
        __syncthreads();
        if (tid == 0) {
            float s_noobj   = s_red[0][0] + s_red[1][0] + s_red[2][0] + s_red[3][0];
            float c_noobj   = s_red[0][1] + s_red[1][1] + s_red[2][1] + s_red[3][1];
            float s_objconf = s_red[0][2] + s_red[1][2] + s_red[2][2] + s_red[3][2];
            float s_xy      = s_red[0][3] + s_red[1][3] + s_red[2][3] + s_red[3][3];
            float s_wh      = s_red[0][4] + s_red[1][4] + s_red[2][4] + s_red[3][4];
            float s_clc     = s_red[0][5] + s_red[1][5] + s_red[2][5] + s_red[3][5];
            float c_obj     = s_red[0][6] + s_red[1][6] + s_red[2][6] + s_red[3][6];

            float n_noobj = 2.0f * c_noobj;      // both boxes of each noobj cell
            float n_resp  = c_obj;               // one responsible box per obj cell
            float noobj_loss   = s_noobj / n_noobj;
            float objconf_loss = s_objconf / n_resp;
            float loss_xy  = s_xy / (n_resp * 2.0f);
            float loss_wh  = s_wh / (n_resp * 2.0f);
            float loss_clc = s_clc / (c_obj * (float)NCLS);
            out[0] = 5.0f * (loss_xy + loss_wh) + objconf_loss
                   + 0.5f * noobj_loss + loss_clc;
        }
    }
}

extern "C" void kernel_launch(void* const* d_in, const int* in_sizes, int n_in,
                              void* d_out, int out_size, void* d_ws, size_t ws_size,
                              hipStream_t stream) {
    const float* pred = (const float*)d_in[0];
    const float* target = (const float*)d_in[1];
    float* partials = (float*)d_ws;                      // 2048*8 f32 = 64 KiB
    unsigned int* counter = (unsigned int*)((char*)d_ws + NBATCH * 8 * sizeof(float));
    float* out = (float*)d_out;

    yolo_fused_kernel<<<NBATCH, 256, 0, stream>>>(pred, target, partials, counter, out);
}

// Round 5
// 23.266 us; speedup vs baseline: 2.5693x; 2.5693x over previous
//
#include <hip/hip_runtime.h>
#include <math.h>

#define NBATCH 2048
#define GS 14
#define NCELL (GS * GS)          // 196
#define NCH 30
#define NPRED (NCELL * NCH)      // 5880 floats per batch
#define NQUAD_TOT (NBATCH * NPRED / 4)   // 3010560 float4s in pred
#define MAXOBJ 20
#define NCLS 20

#define STREAM_BLOCKS 2048
#define OBJ_BLOCKS 512           // 4 waves/block -> 2048 batches
#define THREADS 256

// ws layout (floats):
//   [0, 2048)            : per-stream-block partial of S_all = sum(c0^2+c5^2)
//   [2048, 2048+512*8)   : per-obj-block partials
//     k: 0=s_sub 1=c_occ 2=s_objconf 3=s_xy 4=s_wh 5=s_clc 6=c_obj1 7=0
#define WS_OBJ_OFF 2048

// ---------------------------------------------------------------------------
// Main kernel. Blocks [0,2048): pure coalesced streaming reduction of
// conf0^2+conf1^2 over ALL cells. Blocks [2048,2560): object pass, one wave
// per batch; wave-parallel decode + packed-key shuffle dedup (last-write-wins)
// + sparse float2 gathers of the ~14 obj-cell pred rows.
// No fences, no atomics: the two roles are independent; ordering with the
// final kernel comes from the launch boundary.
// ---------------------------------------------------------------------------
__global__ __launch_bounds__(256) void yolo_main_kernel(
        const float* __restrict__ pred,
        const float* __restrict__ target,
        float* __restrict__ ws)
{
    __shared__ float s_red[4][8];
    const int bid = blockIdx.x;
    const int tid = threadIdx.x;
    const int wave = tid >> 6;
    const int lane = tid & 63;

    if (bid < STREAM_BLOCKS) {
        // ---------------- streaming role ----------------
        float acc = 0.f;
        const float4* g4 = (const float4*)pred;
        const int gtid = bid * THREADS + tid;
        #pragma unroll
        for (int k = 0; k < 6; ++k) {
            int q = gtid + k * (STREAM_BLOCKS * THREADS);
            if (q < NQUAD_TOT) {
                float4 x = g4[q];
                int f = (q * 4) % NCH;           // channel of x.x
                // channels f..f+3 (wrap at 30); conf channels are 0 and 5,
                // so a hit is f+j == 0, 5, or 30.
                float xs0 = x.x, xs1 = x.y, xs2 = x.z, xs3 = x.w;
                if (f == 0 || f == 5 || f == 30) acc += xs0 * xs0;
                int t1 = f + 1; if (t1 == 5 || t1 == 30) acc += xs1 * xs1;
                int t2 = f + 2; if (t2 == 5 || t2 == 30) acc += xs2 * xs2;
                int t3 = f + 3; if (t3 == 5 || t3 == 30) acc += xs3 * xs3;
            }
        }
        #pragma unroll
        for (int off = 32; off > 0; off >>= 1) acc += __shfl_down(acc, off);
        if (lane == 0) s_red[wave][0] = acc;
        __syncthreads();
        if (tid == 0)
            ws[bid] = s_red[0][0] + s_red[1][0] + s_red[2][0] + s_red[3][0];
        return;
    }

    // ---------------- object role ----------------
    const int ob = bid - STREAM_BLOCKS;      // 0..511
    const int b = ob * 4 + wave;             // batch handled by this wave
    const float fg = (float)GS;
    const int o = lane;

    bool valid = false;
    int cell = 0, mi = 0, cls = 0;
    float offx = 0.f, offy = 0.f, w = 0.f, h = 0.f;
    float pc[10];                            // pred channels 0..9 of my cell
    #pragma unroll
    for (int i = 0; i < 10; ++i) pc[i] = 0.f;

    if (o < MAXOBJ) {
        const float* tb = target + (size_t)b * (MAXOBJ * 5) + o * 5;
        float x1 = tb[0], y1 = tb[1], x2 = tb[2], y2 = tb[3], cf = tb[4];
        if ((x1 + y1 + x2 + y2 + cf) != 0.0f) {
            valid = true;
            float cx = (x1 + x2) * 0.5f * fg;
            float cy = (y1 + y2) * 0.5f * fg;
            w = x2 - x1;
            h = y2 - y1;
            int gx = min(max((int)floorf(cx), 0), GS - 1);
            int gy = min(max((int)floorf(cy), 0), GS - 1);
            offx = cx - (float)gx;
            offy = cy - (float)gy;
            cell = gy * GS + gx;
            cls = (int)cf;
            // gather pred channels 0..9 of this cell (8B-aligned float2s)
            const float2* p2 = (const float2*)(pred + ((size_t)b * NCELL + cell) * NCH);
            #pragma unroll
            for (int i = 0; i < 5; ++i) {
                float2 xx = p2[i];
                pc[2 * i] = xx.x;
                pc[2 * i + 1] = xx.y;
            }
            // IoU vs both predicted boxes
            float tcx = offx / fg, tcy = offy / fg;
            float tlx = tcx - 0.5f * w, tly = tcy - 0.5f * h;
            float trx = tcx + 0.5f * w, trY = tcy + 0.5f * h;
            float ta = (trx - tlx) * (trY - tly);
            float iou0, iou1;
            {
                float px = pc[1] / fg, py = pc[2] / fg;
                float pw = pc[3], ph = pc[4];
                float plx = px - 0.5f * pw, ply = py - 0.5f * ph;
                float prx = px + 0.5f * pw, prY = py + 0.5f * ph;
                float ix = fmaxf(fminf(prx, trx) - fmaxf(plx, tlx), 0.f);
                float iy = fmaxf(fminf(prY, trY) - fmaxf(ply, tly), 0.f);
                float inter = ix * iy;
                float a1 = (prx - plx) * (prY - ply);
                iou0 = inter / (a1 + ta - inter);
            }
            {
                float px = pc[6] / fg, py = pc[7] / fg;
                float pw = pc[8], ph = pc[9];
                float plx = px - 0.5f * pw, ply = py - 0.5f * ph;
                float prx = px + 0.5f * pw, prY = py + 0.5f * ph;
                float ix = fmaxf(fminf(prx, trx) - fmaxf(plx, tlx), 0.f);
                float iy = fmaxf(fminf(prY, trY) - fmaxf(ply, tly), 0.f);
                float inter = ix * iy;
                float a1 = (prx - plx) * (prY - ply);
                iou1 = inter / (a1 + ta - inter);
            }
            mi = (iou1 > iou0) ? 1 : 0;      // argmax, first-wins on tie
        }
    }

    // packed key: cell (8b) | mi<<8 | cls<<16
    int pack = cell | (mi << 8) | (cls << 16);
    unsigned long long vm = __ballot(valid);

    // last-write-wins: lane o loses (cell,mi) if a LATER valid lane shares it
    bool win = valid;
    #pragma unroll
    for (int j = 0; j < MAXOBJ; ++j) {
        int pj = __shfl(pack, j);
        if (((vm >> j) & 1ull) && j > o && (pj & 0x1FF) == (pack & 0x1FF))
            win = false;
    }
    unsigned long long wm = __ballot(win);

    // per-cell facts: other-mi winner exists? am I the lowest-lane winner?
    // clsmask = union of classes of ALL valid objects at my cell
    bool other = false;
    bool rep = win;
    unsigned int clsmask = 0u;
    #pragma unroll
    for (int j = 0; j < MAXOBJ; ++j) {
        int pj = __shfl(pack, j);
        int cj = pj & 0xFF;
        int mj = (pj >> 8) & 1;
        int clj = (pj >> 16) & 0xFF;
        bool vj = (vm >> j) & 1ull;
        bool wj = (wm >> j) & 1ull;
        if (wj && cj == cell && mj != mi) other = true;
        if (wj && j < o && cj == cell) rep = false;
        if (vj && cj == cell) clsmask |= (1u << clj);
    }

    // contributions
    float v0 = 0.f, v1 = 0.f, v2 = 0.f, v3 = 0.f, v4 = 0.f, v5 = 0.f, v6 = 0.f;
    if (rep) {                               // once per occupied cell
        v0 = pc[0] * pc[0] + pc[5] * pc[5];  // s_sub
        v1 = 1.0f;                           // c_occ
    }
    if (win && !other) {                     // nset==1 responsible box
        float conf = mi ? pc[5] : pc[0];
        float px   = mi ? pc[6] : pc[1];
        float py   = mi ? pc[7] : pc[2];
        float pw   = mi ? pc[8] : pc[3];
        float ph   = mi ? pc[9] : pc[4];
        float dconf = conf - 1.0f;
        v2 = dconf * dconf;
        float dx = px - offx, dy = py - offy;
        v3 = dx * dx + dy * dy;
        float sw = sqrtf(pw) - sqrtf(w);
        float sh = sqrtf(ph) - sqrtf(h);
        v4 = sw * sw + sh * sh;
        // class SSE: gather channels 10..29
        const float2* p2 = (const float2*)(pred + ((size_t)b * NCELL + cell) * NCH);
        float clc = 0.f;
        #pragma unroll
        for (int k = 0; k < 10; ++k) {
            float2 xx = p2[5 + k];
            float t0 = ((clsmask >> (2 * k)) & 1u) ? 1.0f : 0.0f;
            float t1 = ((clsmask >> (2 * k + 1)) & 1u) ? 1.0f : 0.0f;
            float d0 = xx.x - t0, d1 = xx.y - t1;
            clc += d0 * d0 + d1 * d1;
        }
        v5 = clc;
        v6 = 1.0f;                           // c_obj1
    }

    // wave reduce 7 values
    #pragma unroll
    for (int off = 32; off > 0; off >>= 1) {
        v0 += __shfl_down(v0, off);
        v1 += __shfl_down(v1, off);
        v2 += __shfl_down(v2, off);
        v3 += __shfl_down(v3, off);
        v4 += __shfl_down(v4, off);
        v5 += __shfl_down(v5, off);
        v6 += __shfl_down(v6, off);
    }
    if (lane == 0) {
        s_red[wave][0] = v0; s_red[wave][1] = v1; s_red[wave][2] = v2;
        s_red[wave][3] = v3; s_red[wave][4] = v4; s_red[wave][5] = v5;
        s_red[wave][6] = v6;
    }
    __syncthreads();
    if (tid == 0) {
        float* p = ws + WS_OBJ_OFF + (size_t)ob * 8;
        #pragma unroll
        for (int k = 0; k < 7; ++k)
            p[k] = s_red[0][k] + s_red[1][k] + s_red[2][k] + s_red[3][k];
        p[7] = 0.0f;
    }
}

// ---------------------------------------------------------------------------
// Final kernel: deterministic fixed-order reduction + loss formula.
// ---------------------------------------------------------------------------
__global__ __launch_bounds__(256) void yolo_final_kernel(
        const float* __restrict__ ws,
        float* __restrict__ out)
{
    __shared__ float s_red[4][8];
    const int tid = threadIdx.x;
    const int wave = tid >> 6;
    const int lane = tid & 63;

    float sa = 0.f;
    for (int r = tid; r < STREAM_BLOCKS; r += THREADS) sa += ws[r];

    float v[7] = {0.f, 0.f, 0.f, 0.f, 0.f, 0.f, 0.f};
    for (int r = tid; r < OBJ_BLOCKS; r += THREADS) {
        const float* p = ws + WS_OBJ_OFF + (size_t)r * 8;
        #pragma unroll
        for (int k = 0; k < 7; ++k) v[k] += p[k];
    }

    #pragma unroll
    for (int off = 32; off > 0; off >>= 1) {
        sa += __shfl_down(sa, off);
        #pragma unroll
        for (int k = 0; k < 7; ++k) v[k] += __shfl_down(v[k], off);
    }
    if (lane == 0) {
        s_red[wave][0] = v[0]; s_red[wave][1] = v[1]; s_red[wave][2] = v[2];
        s_red[wave][3] = v[3]; s_red[wave][4] = v[4]; s_red[wave][5] = v[5];
        s_red[wave][6] = v[6]; s_red[wave][7] = sa;
    }
    __syncthreads();
    if (tid == 0) {
        float s_sub     = s_red[0][0] + s_red[1][0] + s_red[2][0] + s_red[3][0];
        float c_occ     = s_red[0][1] + s_red[1][1] + s_red[2][1] + s_red[3][1];
        float s_objconf = s_red[0][2] + s_red[1][2] + s_red[2][2] + s_red[3][2];
        float s_xy      = s_red[0][3] + s_red[1][3] + s_red[2][3] + s_red[3][3];
        float s_wh      = s_red[0][4] + s_red[1][4] + s_red[2][4] + s_red[3][4];
        float s_clc     = s_red[0][5] + s_red[1][5] + s_red[2][5] + s_red[3][5];
        float c_obj1    = s_red[0][6] + s_red[1][6] + s_red[2][6] + s_red[3][6];
        float s_all     = s_red[0][7] + s_red[1][7] + s_red[2][7] + s_red[3][7];

        float s_noobj = s_all - s_sub;
        float c_noobj = (float)(NBATCH * NCELL) - c_occ;
        float n_noobj = 2.0f * c_noobj;
        float n_resp  = c_obj1;
        float noobj_loss   = s_noobj / n_noobj;
        float objconf_loss = s_objconf / n_resp;
        float loss_xy  = s_xy / (n_resp * 2.0f);
        float loss_wh  = s_wh / (n_resp * 2.0f);
        float loss_clc = s_clc / (c_obj1 * (float)NCLS);
        out[0] = 5.0f * (loss_xy + loss_wh) + objconf_loss
               + 0.5f * noobj_loss + loss_clc;
    }
}

extern "C" void kernel_launch(void* const* d_in, const int* in_sizes, int n_in,
                              void* d_out, int out_size, void* d_ws, size_t ws_size,
                              hipStream_t stream) {
    const float* pred = (const float*)d_in[0];
    const float* target = (const float*)d_in[1];
    float* ws = (float*)d_ws;     // 2048 + 512*8 floats = 24 KiB, fully overwritten
    float* out = (float*)d_out;

    yolo_main_kernel<<<STREAM_BLOCKS + OBJ_BLOCKS, THREADS, 0, stream>>>(pred, target, ws);
    yolo_final_kernel<<<1, THREADS, 0, stream>>>(ws, out);
}